// Round 3
// baseline (615.570 us; speedup 1.0000x reference)
//
#include <hip/hip_runtime.h>

#define D 128
#define BN_EPS 1e-5f

// ---------------------------------------------------------------------------
// K1: in-degree via atomics.  deg must be zeroed beforehand.
// NOTE: harness delivers integer inputs as int32 (not int64!).
__global__ __launch_bounds__(256) void degree_kernel(
    const int* __restrict__ col, float* __restrict__ deg, int E) {
  int e = blockIdx.x * 256 + threadIdx.x;
  if (e < E) atomicAdd(&deg[col[e]], 1.0f);
}

// K2: deg -> deg^{-1/2} in place (0 if deg==0)
__global__ __launch_bounds__(256) void dis_kernel(float* __restrict__ deg, int N) {
  int n = blockIdx.x * 256 + threadIdx.x;
  if (n < N) {
    float d = deg[n];
    deg[n] = (d > 0.0f) ? rsqrtf(fmaxf(d, 1.0f)) : 0.0f;
  }
}

// K3: scatter x (pre-GEMM; aggregation commutes with the linear transform).
// out[c] += x[r] * dis[r]*dis[c].  Block = 256 threads = 2 edges x 128 feats.
__global__ __launch_bounds__(256) void scatter_kernel(
    const int* __restrict__ ei, const float* __restrict__ x,
    const float* __restrict__ dis, float* __restrict__ out, int E) {
  int e = blockIdx.x * 2 + (threadIdx.x >> 7);
  int d = threadIdx.x & 127;
  if (e >= E) return;
  int r = ei[e];
  int c = ei[E + e];
  float norm = dis[r] * dis[c];
  float v = x[(size_t)r * D + d] * norm;
  atomicAdd(&out[(size_t)c * D + d], v);
}

// K4: in-place row GEMM: out_row <- out_row @ W.
// Each block owns 2 rows; rows staged in LDS before overwrite, so in-place
// is safe (each output row depends only on the same input row).
__global__ __launch_bounds__(256) void gemm_inplace_kernel(
    const float* __restrict__ W, float* __restrict__ out, int N) {
  __shared__ float xs[2][D];
  int t  = threadIdx.x;
  int lr = t >> 7;       // local row 0..1
  int d  = t & 127;      // feature
  int n  = blockIdx.x * 2 + lr;
  if (n < N) xs[lr][d] = out[(size_t)n * D + d];
  __syncthreads();
  if (n < N) {
    float acc = 0.0f;
#pragma unroll 8
    for (int k = 0; k < D; ++k)
      acc = fmaf(xs[lr][k], W[k * D + d], acc);
    out[(size_t)n * D + d] = acc;
  }
}

// K5: per-feature partial sums / sumsq over a 64-row stripe -> atomics.
// sums[0..D) = sum, sums[D..2D) = sumsq.  (conv bias b cancels in BN.)
#define ROWS_PER_BLOCK 64
__global__ __launch_bounds__(256) void bn_stats_kernel(
    const float* __restrict__ agg, float* __restrict__ sums, int N) {
  int d = threadIdx.x & 127;
  int g = threadIdx.x >> 7;  // 0..1
  int row0 = blockIdx.x * ROWS_PER_BLOCK;
  int rend = min(row0 + ROWS_PER_BLOCK, N);
  float s = 0.0f, sq = 0.0f;
  for (int r = row0 + g; r < rend; r += 2) {
    float v = agg[(size_t)r * D + d];
    s += v;
    sq += v * v;
  }
  atomicAdd(&sums[d], s);
  atomicAdd(&sums[D + d], sq);
}

// K6: finalize mean / inv_std  (1 block, 128 threads)
__global__ void bn_finalize_kernel(const float* __restrict__ sums,
                                   float* __restrict__ mv, int N) {
  int d = threadIdx.x;
  if (d < D) {
    float inv_n = 1.0f / (float)N;
    float mean = sums[d] * inv_n;
    float var = sums[D + d] * inv_n - mean * mean;
    mv[d] = mean;
    mv[D + d] = rsqrtf(fmaxf(var, 0.0f) + BN_EPS);
  }
}

// K7: out = relu((agg - mean)*inv_std*gamma + beta) + x     (in place on d_out)
__global__ __launch_bounds__(256) void final_kernel(
    const float* __restrict__ x, const float* __restrict__ mv,
    const float* __restrict__ gamma, const float* __restrict__ beta,
    float* __restrict__ out, int total) {
  int i = blockIdx.x * 256 + threadIdx.x;
  if (i >= total) return;
  int d = i & 127;
  float v = out[i];
  float hn = (v - mv[d]) * mv[D + d] * gamma[d] + beta[d];
  out[i] = fmaxf(hn, 0.0f) + x[i];
}

extern "C" void kernel_launch(void* const* d_in, const int* in_sizes, int n_in,
                              void* d_out, int out_size, void* d_ws, size_t ws_size,
                              hipStream_t stream) {
  const float* x     = (const float*)d_in[0];
  const int*   ei    = (const int*)d_in[1];   // int32! (harness converts ints)
  const float* W     = (const float*)d_in[2];
  // d_in[3] = b : algebraically cancelled by BatchNorm, skipped.
  const float* gamma = (const float*)d_in[4];
  const float* beta  = (const float*)d_in[5];

  const int N = in_sizes[0] / D;      // 100000
  const int E = in_sizes[1] / 2;      // 600000

  float* out = (float*)d_out;         // doubles as agg buffer

  // tiny workspace: deg[N] + sums[2D] + mv[2D]  (~402 KB)
  float* deg  = (float*)d_ws;
  float* sums = deg + N;
  float* mv   = sums + 2 * D;

  hipMemsetAsync(deg, 0, (size_t)N * sizeof(float), stream);
  hipMemsetAsync(sums, 0, 2 * D * sizeof(float), stream);
  hipMemsetAsync(out, 0, (size_t)out_size * sizeof(float), stream);

  degree_kernel<<<(E + 255) / 256, 256, 0, stream>>>(ei + E, deg, E);
  dis_kernel<<<(N + 255) / 256, 256, 0, stream>>>(deg, N);
  scatter_kernel<<<(E + 1) / 2, 256, 0, stream>>>(ei, x, deg, out, E);
  gemm_inplace_kernel<<<(N + 1) / 2, 256, 0, stream>>>(W, out, N);
  bn_stats_kernel<<<(N + ROWS_PER_BLOCK - 1) / ROWS_PER_BLOCK, 256, 0, stream>>>(out, sums, N);
  bn_finalize_kernel<<<1, 128, 0, stream>>>(sums, mv, N);
  final_kernel<<<(out_size + 255) / 256, 256, 0, stream>>>(x, mv, gamma, beta, out, out_size);
}

// Round 4
// 245.920 us; speedup vs baseline: 2.5031x; 2.5031x over previous
//
#include <hip/hip_runtime.h>

#define D 128
#define BN_EPS 1e-5f
#define GEMM_GRID 512

// ============================ CSR build ====================================
__global__ __launch_bounds__(256) void degree_i_kernel(
    const int* __restrict__ col, int* __restrict__ cnt, int E) {
  int e = blockIdx.x * 256 + threadIdx.x;
  if (e < E) atomicAdd(&cnt[col[e]], 1);
}

// per-block sums of cnt + dis = rsqrt(cnt)
__global__ __launch_bounds__(256) void scanA_kernel(
    const int* __restrict__ cnt, float* __restrict__ dis,
    int* __restrict__ partials, int N) {
  __shared__ int l[256];
  int t = threadIdx.x;
  int i = blockIdx.x * 256 + t;
  int v = (i < N) ? cnt[i] : 0;
  if (i < N) dis[i] = (v > 0) ? rsqrtf((float)v) : 0.0f;
  l[t] = v; __syncthreads();
  for (int s = 128; s > 0; s >>= 1) {
    if (t < s) l[t] += l[t + s];
    __syncthreads();
  }
  if (t == 0) partials[blockIdx.x] = l[0];
}

// single-block exclusive scan of partials (nb <= 512)
__global__ void scanB_kernel(int* __restrict__ partials, int nb) {
  __shared__ int l[512];
  int t = threadIdx.x;
  l[t] = (t < nb) ? partials[t] : 0;
  __syncthreads();
  for (int off = 1; off < 512; off <<= 1) {
    int v = (t >= off) ? l[t - off] : 0;
    __syncthreads();
    l[t] += v;
    __syncthreads();
  }
  if (t < nb) partials[t] = (t == 0) ? 0 : l[t - 1];
}

// per-element exclusive offsets
__global__ __launch_bounds__(256) void scanC_kernel(
    const int* __restrict__ cnt, const int* __restrict__ partials,
    int* __restrict__ offsets, int N) {
  __shared__ int l[256];
  int t = threadIdx.x;
  int i = blockIdx.x * 256 + t;
  int v = (i < N) ? cnt[i] : 0;
  l[t] = v; __syncthreads();
  for (int off = 1; off < 256; off <<= 1) {
    int u = (t >= off) ? l[t - off] : 0;
    __syncthreads();
    l[t] += u;
    __syncthreads();
  }
  if (i < N) offsets[i] = partials[blockIdx.x] + l[t] - v;
}

// scatter edge source-ids into destination-sorted order
__global__ __launch_bounds__(256) void bucket_kernel(
    const int* __restrict__ ei, const int* __restrict__ offsets,
    int* __restrict__ cursor, int* __restrict__ csr_row, int E) {
  int e = blockIdx.x * 256 + threadIdx.x;
  if (e < E) {
    int c = ei[E + e];
    int p = offsets[c] + atomicAdd(&cursor[c], 1);
    csr_row[p] = ei[e];
  }
}

// ================= aggregation: gather rows, write once ====================
// one wave per node; lane handles float2 of the 128-wide row (512B coalesced)
__global__ __launch_bounds__(256) void csr_agg_kernel(
    const int* __restrict__ csr_row, const int* __restrict__ offsets,
    const float* __restrict__ dis, const float* __restrict__ x,
    float* __restrict__ out, int N, int E) {
  int wave = threadIdx.x >> 6;
  int lane = threadIdx.x & 63;
  int c = blockIdx.x * 4 + wave;
  if (c >= N) return;
  int s = offsets[c];
  int e = (c + 1 < N) ? offsets[c + 1] : E;
  const float2* x2 = (const float2*)x;
  float ax = 0.f, ay = 0.f;
  for (int i = s; i < e; ++i) {
    int r = csr_row[i];
    float w = dis[r];
    float2 v = x2[(size_t)r * 64 + lane];
    ax = fmaf(w, v.x, ax);
    ay = fmaf(w, v.y, ay);
  }
  float wc = dis[c];
  ((float2*)out)[(size_t)c * 64 + lane] = make_float2(ax * wc, ay * wc);
}

// ====================== fallback aggregation (atomics) =====================
__global__ __launch_bounds__(256) void degree_f_kernel(
    const int* __restrict__ col, float* __restrict__ deg, int E) {
  int e = blockIdx.x * 256 + threadIdx.x;
  if (e < E) atomicAdd(&deg[col[e]], 1.0f);
}
__global__ __launch_bounds__(256) void dis_kernel(float* __restrict__ deg, int N) {
  int n = blockIdx.x * 256 + threadIdx.x;
  if (n < N) {
    float d = deg[n];
    deg[n] = (d > 0.0f) ? rsqrtf(fmaxf(d, 1.0f)) : 0.0f;
  }
}
__global__ __launch_bounds__(256) void scatter_kernel(
    const int* __restrict__ ei, const float* __restrict__ x,
    const float* __restrict__ dis, float* __restrict__ out, int E) {
  int e = blockIdx.x * 2 + (threadIdx.x >> 7);
  int d = threadIdx.x & 127;
  if (e >= E) return;
  int r = ei[e];
  int c = ei[E + e];
  float norm = dis[r] * dis[c];
  atomicAdd(&out[(size_t)c * D + d], x[(size_t)r * D + d] * norm);
}

// ============ in-place GEMM (W staged in LDS) + fused BN stats =============
// 256 threads: thread = (rp = t>>5 -> rows 2rp,2rp+1 of 16-row tile,
//                        cq = t&31 -> cols 4cq..4cq+3)
__global__ __launch_bounds__(256) void gemm_stats_kernel(
    const float* __restrict__ W, float* __restrict__ out,
    float* __restrict__ sums, int N) {
  __shared__ float Wl[D * D];     // 64 KB
  __shared__ float xs[16][D];     // 8 KB
  int t = threadIdx.x;
  {
    const float4* W4 = (const float4*)W;
    float4* Wl4w = (float4*)Wl;
#pragma unroll
    for (int i = 0; i < 16; ++i)
      Wl4w[i * 256 + t] = W4[i * 256 + t];
  }
  const float4* Wl4 = (const float4*)Wl;
  int rp = t >> 5;
  int cq = t & 31;
  float sA0=0,sA1=0,sA2=0,sA3=0, sQ0=0,sQ1=0,sQ2=0,sQ3=0;
  __syncthreads();

  for (int base = blockIdx.x * 16; base < N; base += GEMM_GRID * 16) {
    int nrows = min(16, N - base);
    for (int i = t; i < nrows * D; i += 256)
      xs[i >> 7][i & 127] = out[(size_t)base * D + i];
    __syncthreads();
    int r0 = rp * 2, r1 = rp * 2 + 1;
    float a00=0,a01=0,a02=0,a03=0, a10=0,a11=0,a12=0,a13=0;
#pragma unroll 4
    for (int k = 0; k < D; ++k) {
      float4 wv = Wl4[k * 32 + cq];
      float x0 = xs[r0][k];
      float x1 = xs[r1][k];
      a00 = fmaf(x0, wv.x, a00); a01 = fmaf(x0, wv.y, a01);
      a02 = fmaf(x0, wv.z, a02); a03 = fmaf(x0, wv.w, a03);
      a10 = fmaf(x1, wv.x, a10); a11 = fmaf(x1, wv.y, a11);
      a12 = fmaf(x1, wv.z, a12); a13 = fmaf(x1, wv.w, a13);
    }
    float4* o4 = (float4*)out;
    if (r0 < nrows) {
      o4[(size_t)(base + r0) * 32 + cq] = make_float4(a00, a01, a02, a03);
      sA0+=a00; sA1+=a01; sA2+=a02; sA3+=a03;
      sQ0+=a00*a00; sQ1+=a01*a01; sQ2+=a02*a02; sQ3+=a03*a03;
    }
    if (r1 < nrows) {
      o4[(size_t)(base + r1) * 32 + cq] = make_float4(a10, a11, a12, a13);
      sA0+=a10; sA1+=a11; sA2+=a12; sA3+=a13;
      sQ0+=a10*a10; sQ1+=a11*a11; sQ2+=a12*a12; sQ3+=a13*a13;
    }
    __syncthreads();
  }
  // block-level stats reduction (reuse xs), one atomic per feature per block
  xs[rp][cq*4+0]=sA0; xs[rp][cq*4+1]=sA1; xs[rp][cq*4+2]=sA2; xs[rp][cq*4+3]=sA3;
  __syncthreads();
  if (t < D) {
    float v = 0;
#pragma unroll
    for (int r = 0; r < 8; ++r) v += xs[r][t];
    atomicAdd(&sums[t], v);
  }
  __syncthreads();
  xs[rp][cq*4+0]=sQ0; xs[rp][cq*4+1]=sQ1; xs[rp][cq*4+2]=sQ2; xs[rp][cq*4+3]=sQ3;
  __syncthreads();
  if (t < D) {
    float v = 0;
#pragma unroll
    for (int r = 0; r < 8; ++r) v += xs[r][t];
    atomicAdd(&sums[D + t], v);
  }
}

// ====================== BN finalize + fused epilogue =======================
__global__ void bn_finalize_kernel(const float* __restrict__ sums,
                                   float* __restrict__ mv, int N) {
  int d = threadIdx.x;
  if (d < D) {
    float inv_n = 1.0f / (float)N;
    float mean = sums[d] * inv_n;
    float var = sums[D + d] * inv_n - mean * mean;
    mv[d] = mean;
    mv[D + d] = rsqrtf(fmaxf(var, 0.0f) + BN_EPS);
  }
}

__global__ __launch_bounds__(256) void final4_kernel(
    const float* __restrict__ x, const float* __restrict__ mv,
    const float* __restrict__ gamma, const float* __restrict__ beta,
    float* __restrict__ out, int total4) {
  int i = blockIdx.x * 256 + threadIdx.x;
  if (i >= total4) return;
  int q = i & 31;
  float4 m4 = ((const float4*)mv)[q];
  float4 s4 = ((const float4*)mv)[32 + q];
  float4 g4 = ((const float4*)gamma)[q];
  float4 b4 = ((const float4*)beta)[q];
  float4 v  = ((const float4*)out)[i];
  float4 xv = ((const float4*)x)[i];
  float4 r;
  r.x = fmaxf((v.x - m4.x) * s4.x * g4.x + b4.x, 0.f) + xv.x;
  r.y = fmaxf((v.y - m4.y) * s4.y * g4.y + b4.y, 0.f) + xv.y;
  r.z = fmaxf((v.z - m4.z) * s4.z * g4.z + b4.z, 0.f) + xv.z;
  r.w = fmaxf((v.w - m4.w) * s4.w * g4.w + b4.w, 0.f) + xv.w;
  ((float4*)out)[i] = r;
}

// ===========================================================================
extern "C" void kernel_launch(void* const* d_in, const int* in_sizes, int n_in,
                              void* d_out, int out_size, void* d_ws, size_t ws_size,
                              hipStream_t stream) {
  const float* x     = (const float*)d_in[0];
  const int*   ei    = (const int*)d_in[1];   // int32 (harness converts ints)
  const float* W     = (const float*)d_in[2];
  // d_in[3] = b : cancels in BatchNorm (constant per-feature shift), skipped.
  const float* gamma = (const float*)d_in[4];
  const float* beta  = (const float*)d_in[5];

  const int N = in_sizes[0] / D;   // 100000
  const int E = in_sizes[1] / 2;   // 600000
  const int NB = (N + 255) / 256;

  float* out = (float*)d_out;      // doubles as agg buffer
  char* ws = (char*)d_ws;

  size_t need = ((size_t)3 * N + 512 + (size_t)E + 4 * D) * sizeof(float);

  if (ws_size >= need && NB <= 512) {
    // ---- CSR path (no f32 atomics in the hot loop) ----
    int*   cnt      = (int*)ws;            // N   (reused as cursor)
    int*   offsets  = cnt + N;             // N
    float* dis      = (float*)(offsets + N); // N
    int*   partials = (int*)(dis + N);     // 512
    int*   csr_row  = partials + 512;      // E
    float* sums     = (float*)(csr_row + E); // 2D
    float* mv       = sums + 2 * D;        // 2D

    hipMemsetAsync(cnt, 0, (size_t)N * sizeof(int), stream);
    hipMemsetAsync(sums, 0, 2 * D * sizeof(float), stream);

    degree_i_kernel<<<(E + 255) / 256, 256, 0, stream>>>(ei + E, cnt, E);
    scanA_kernel<<<NB, 256, 0, stream>>>(cnt, dis, partials, N);
    scanB_kernel<<<1, 512, 0, stream>>>(partials, NB);
    scanC_kernel<<<NB, 256, 0, stream>>>(cnt, partials, offsets, N);
    hipMemsetAsync(cnt, 0, (size_t)N * sizeof(int), stream);  // -> cursor
    bucket_kernel<<<(E + 255) / 256, 256, 0, stream>>>(ei, offsets, cnt, csr_row, E);
    csr_agg_kernel<<<(N + 3) / 4, 256, 0, stream>>>(csr_row, offsets, dis, x, out, N, E);
    gemm_stats_kernel<<<GEMM_GRID, 256, 0, stream>>>(W, out, sums, N);
    bn_finalize_kernel<<<1, 128, 0, stream>>>(sums, mv, N);
    final4_kernel<<<(N * 32 + 255) / 256, 256, 0, stream>>>(x, mv, gamma, beta, out, N * 32);
  } else {
    // ---- fallback: proven atomic-scatter path ----
    float* deg  = (float*)ws;
    float* sums = deg + N;
    float* mv   = sums + 2 * D;
    hipMemsetAsync(deg, 0, (size_t)N * sizeof(float), stream);
    hipMemsetAsync(sums, 0, 2 * D * sizeof(float), stream);
    hipMemsetAsync(out, 0, (size_t)out_size * sizeof(float), stream);
    degree_f_kernel<<<(E + 255) / 256, 256, 0, stream>>>(ei + E, deg, E);
    dis_kernel<<<(N + 255) / 256, 256, 0, stream>>>(deg, N);
    scatter_kernel<<<(E + 1) / 2, 256, 0, stream>>>(ei, x, deg, out, E);
    gemm_stats_kernel<<<GEMM_GRID, 256, 0, stream>>>(W, out, sums, N);
    bn_finalize_kernel<<<1, 128, 0, stream>>>(sums, mv, N);
    final4_kernel<<<(N * 32 + 255) / 256, 256, 0, stream>>>(x, mv, gamma, beta, out, N * 32);
  }
}

// Round 5
// 244.679 us; speedup vs baseline: 2.5158x; 1.0051x over previous
//
#include <hip/hip_runtime.h>

#define D 128
#define BN_EPS 1e-5f
#define GEMM_GRID 512
#define GEMM_TILE 32

// ============================ CSR build ====================================
__global__ __launch_bounds__(256) void degree_i_kernel(
    const int* __restrict__ col, int* __restrict__ cnt, int E) {
  int e = blockIdx.x * 256 + threadIdx.x;
  if (e < E) atomicAdd(&cnt[col[e]], 1);
}

// per-block sums of cnt + dis = rsqrt(cnt)
__global__ __launch_bounds__(256) void scanA_kernel(
    const int* __restrict__ cnt, float* __restrict__ dis,
    int* __restrict__ partials, int N) {
  __shared__ int l[256];
  int t = threadIdx.x;
  int i = blockIdx.x * 256 + t;
  int v = (i < N) ? cnt[i] : 0;
  if (i < N) dis[i] = (v > 0) ? rsqrtf((float)v) : 0.0f;
  l[t] = v; __syncthreads();
  for (int s = 128; s > 0; s >>= 1) {
    if (t < s) l[t] += l[t + s];
    __syncthreads();
  }
  if (t == 0) partials[blockIdx.x] = l[0];
}

// single-block exclusive scan of partials (nb <= 512)
__global__ void scanB_kernel(int* __restrict__ partials, int nb) {
  __shared__ int l[512];
  int t = threadIdx.x;
  l[t] = (t < nb) ? partials[t] : 0;
  __syncthreads();
  for (int off = 1; off < 512; off <<= 1) {
    int v = (t >= off) ? l[t - off] : 0;
    __syncthreads();
    l[t] += v;
    __syncthreads();
  }
  if (t < nb) partials[t] = (t == 0) ? 0 : l[t - 1];
}

// per-element exclusive offsets
__global__ __launch_bounds__(256) void scanC_kernel(
    const int* __restrict__ cnt, const int* __restrict__ partials,
    int* __restrict__ offsets, int N) {
  __shared__ int l[256];
  int t = threadIdx.x;
  int i = blockIdx.x * 256 + t;
  int v = (i < N) ? cnt[i] : 0;
  l[t] = v; __syncthreads();
  for (int off = 1; off < 256; off <<= 1) {
    int u = (t >= off) ? l[t - off] : 0;
    __syncthreads();
    l[t] += u;
    __syncthreads();
  }
  if (i < N) offsets[i] = partials[blockIdx.x] + l[t] - v;
}

// scatter edge source-ids into destination-sorted order
__global__ __launch_bounds__(256) void bucket_kernel(
    const int* __restrict__ ei, const int* __restrict__ offsets,
    int* __restrict__ cursor, int* __restrict__ csr_row, int E) {
  int e = blockIdx.x * 256 + threadIdx.x;
  if (e < E) {
    int c = ei[E + e];
    int p = offsets[c] + atomicAdd(&cursor[c], 1);
    csr_row[p] = ei[e];
  }
}

// ================= aggregation: gather rows, write once ====================
// one wave per node; 32 lanes x float4 = 512B row; half-wave per edge and
// unroll-by-2 per half-wave -> 4 row-gathers in flight per wave.
__global__ __launch_bounds__(256) void csr_agg_kernel(
    const int* __restrict__ csr_row, const int* __restrict__ offsets,
    const float* __restrict__ dis, const float* __restrict__ x,
    float* __restrict__ out, int N, int E) {
  int wave = threadIdx.x >> 6;
  int lane = threadIdx.x & 63;
  int half = lane >> 5;     // which edge of the pair
  int d4   = lane & 31;     // float4 index within row
  int c = blockIdx.x * 4 + wave;
  if (c >= N) return;
  int s = offsets[c];
  int e = (c + 1 < N) ? offsets[c + 1] : E;
  const float4* x4 = (const float4*)x;
  float4 a0 = {0.f, 0.f, 0.f, 0.f};
  float4 a1 = {0.f, 0.f, 0.f, 0.f};
  int i = s + half;
  for (; i + 2 < e; i += 4) {
    int r0 = csr_row[i];
    int r1 = csr_row[i + 2];
    float w0 = dis[r0];
    float w1 = dis[r1];
    float4 v0 = x4[(size_t)r0 * 32 + d4];
    float4 v1 = x4[(size_t)r1 * 32 + d4];
    a0.x = fmaf(w0, v0.x, a0.x); a0.y = fmaf(w0, v0.y, a0.y);
    a0.z = fmaf(w0, v0.z, a0.z); a0.w = fmaf(w0, v0.w, a0.w);
    a1.x = fmaf(w1, v1.x, a1.x); a1.y = fmaf(w1, v1.y, a1.y);
    a1.z = fmaf(w1, v1.z, a1.z); a1.w = fmaf(w1, v1.w, a1.w);
  }
  if (i < e) {
    int r = csr_row[i];
    float w = dis[r];
    float4 v = x4[(size_t)r * 32 + d4];
    a0.x = fmaf(w, v.x, a0.x); a0.y = fmaf(w, v.y, a0.y);
    a0.z = fmaf(w, v.z, a0.z); a0.w = fmaf(w, v.w, a0.w);
  }
  a0.x += a1.x; a0.y += a1.y; a0.z += a1.z; a0.w += a1.w;
  // combine the two half-waves (lane L <-> L^32 hold the same d4)
  a0.x += __shfl_xor(a0.x, 32, 64);
  a0.y += __shfl_xor(a0.y, 32, 64);
  a0.z += __shfl_xor(a0.z, 32, 64);
  a0.w += __shfl_xor(a0.w, 32, 64);
  if (half == 0) {
    float wc = dis[c];
    a0.x *= wc; a0.y *= wc; a0.z *= wc; a0.w *= wc;
    ((float4*)out)[(size_t)c * 32 + d4] = a0;
  }
}

// ====================== fallback aggregation (atomics) =====================
__global__ __launch_bounds__(256) void degree_f_kernel(
    const int* __restrict__ col, float* __restrict__ deg, int E) {
  int e = blockIdx.x * 256 + threadIdx.x;
  if (e < E) atomicAdd(&deg[col[e]], 1.0f);
}
__global__ __launch_bounds__(256) void dis_kernel(float* __restrict__ deg, int N) {
  int n = blockIdx.x * 256 + threadIdx.x;
  if (n < N) {
    float d = deg[n];
    deg[n] = (d > 0.0f) ? rsqrtf(fmaxf(d, 1.0f)) : 0.0f;
  }
}
__global__ __launch_bounds__(256) void scatter_kernel(
    const int* __restrict__ ei, const float* __restrict__ x,
    const float* __restrict__ dis, float* __restrict__ out, int E) {
  int e = blockIdx.x * 2 + (threadIdx.x >> 7);
  int d = threadIdx.x & 127;
  if (e >= E) return;
  int r = ei[e];
  int c = ei[E + e];
  float norm = dis[r] * dis[c];
  atomicAdd(&out[(size_t)c * D + d], x[(size_t)r * D + d] * norm);
}

// ============ in-place GEMM (W staged in LDS) + fused BN stats =============
// 256 threads: rp = t>>5 -> rows 4rp..4rp+3 of a 32-row tile,
//              cq = t&31 -> cols 4cq..4cq+3.  All LDS reads are b128.
__global__ __launch_bounds__(256) void gemm_stats_kernel(
    const float* __restrict__ W, float* __restrict__ out,
    float* __restrict__ sums, int N) {
  __shared__ float Wl[D * D];                 // 64 KB
  __shared__ float4 xs4[GEMM_TILE][D / 4];    // 16 KB
  int t = threadIdx.x;
  {
    const float4* W4 = (const float4*)W;
    float4* Wl4w = (float4*)Wl;
#pragma unroll
    for (int i = 0; i < 16; ++i)
      Wl4w[i * 256 + t] = W4[i * 256 + t];
  }
  const float4* Wl4 = (const float4*)Wl;
  int rp = t >> 5;
  int cq = t & 31;
  int r0 = rp * 4;
  float sA0=0,sA1=0,sA2=0,sA3=0, sQ0=0,sQ1=0,sQ2=0,sQ3=0;
  __syncthreads();

  for (int base = blockIdx.x * GEMM_TILE; base < N; base += GEMM_GRID * GEMM_TILE) {
    int nrows = min(GEMM_TILE, N - base);
    for (int i = t; i < nrows * 32; i += 256)
      ((float4*)xs4)[i] = ((const float4*)out)[(size_t)base * 32 + i];
    __syncthreads();

    float acc[4][4] = {};
    for (int k4 = 0; k4 < 32; ++k4) {
      float4 wv0 = Wl4[(k4 * 4 + 0) * 32 + cq];
      float4 wv1 = Wl4[(k4 * 4 + 1) * 32 + cq];
      float4 wv2 = Wl4[(k4 * 4 + 2) * 32 + cq];
      float4 wv3 = Wl4[(k4 * 4 + 3) * 32 + cq];
#pragma unroll
      for (int rr = 0; rr < 4; ++rr) {
        float4 xv = xs4[r0 + rr][k4];
        acc[rr][0] = fmaf(xv.x, wv0.x, acc[rr][0]);
        acc[rr][1] = fmaf(xv.x, wv0.y, acc[rr][1]);
        acc[rr][2] = fmaf(xv.x, wv0.z, acc[rr][2]);
        acc[rr][3] = fmaf(xv.x, wv0.w, acc[rr][3]);
        acc[rr][0] = fmaf(xv.y, wv1.x, acc[rr][0]);
        acc[rr][1] = fmaf(xv.y, wv1.y, acc[rr][1]);
        acc[rr][2] = fmaf(xv.y, wv1.z, acc[rr][2]);
        acc[rr][3] = fmaf(xv.y, wv1.w, acc[rr][3]);
        acc[rr][0] = fmaf(xv.z, wv2.x, acc[rr][0]);
        acc[rr][1] = fmaf(xv.z, wv2.y, acc[rr][1]);
        acc[rr][2] = fmaf(xv.z, wv2.z, acc[rr][2]);
        acc[rr][3] = fmaf(xv.z, wv2.w, acc[rr][3]);
        acc[rr][0] = fmaf(xv.w, wv3.x, acc[rr][0]);
        acc[rr][1] = fmaf(xv.w, wv3.y, acc[rr][1]);
        acc[rr][2] = fmaf(xv.w, wv3.z, acc[rr][2]);
        acc[rr][3] = fmaf(xv.w, wv3.w, acc[rr][3]);
      }
    }
    __syncthreads();   // xs4 consumed; safe before next stage

    float4* o4 = (float4*)out;
#pragma unroll
    for (int rr = 0; rr < 4; ++rr) {
      if (r0 + rr < nrows) {
        o4[(size_t)(base + r0 + rr) * 32 + cq] =
            make_float4(acc[rr][0], acc[rr][1], acc[rr][2], acc[rr][3]);
        sA0 += acc[rr][0]; sA1 += acc[rr][1]; sA2 += acc[rr][2]; sA3 += acc[rr][3];
        sQ0 += acc[rr][0]*acc[rr][0]; sQ1 += acc[rr][1]*acc[rr][1];
        sQ2 += acc[rr][2]*acc[rr][2]; sQ3 += acc[rr][3]*acc[rr][3];
      }
    }
  }

  // block-level stats reduction: 8 rp-groups -> 1, then 8 atomics/thread-col
  float4* red = (float4*)xs4;
  __syncthreads();
  red[t] = make_float4(sA0, sA1, sA2, sA3);
  __syncthreads();
  if (rp == 0) {
    float4 v = red[cq];
#pragma unroll
    for (int r = 1; r < 8; ++r) {
      float4 u = red[r * 32 + cq];
      v.x += u.x; v.y += u.y; v.z += u.z; v.w += u.w;
    }
    atomicAdd(&sums[4 * cq + 0], v.x);
    atomicAdd(&sums[4 * cq + 1], v.y);
    atomicAdd(&sums[4 * cq + 2], v.z);
    atomicAdd(&sums[4 * cq + 3], v.w);
  }
  __syncthreads();
  red[t] = make_float4(sQ0, sQ1, sQ2, sQ3);
  __syncthreads();
  if (rp == 0) {
    float4 v = red[cq];
#pragma unroll
    for (int r = 1; r < 8; ++r) {
      float4 u = red[r * 32 + cq];
      v.x += u.x; v.y += u.y; v.z += u.z; v.w += u.w;
    }
    atomicAdd(&sums[D + 4 * cq + 0], v.x);
    atomicAdd(&sums[D + 4 * cq + 1], v.y);
    atomicAdd(&sums[D + 4 * cq + 2], v.z);
    atomicAdd(&sums[D + 4 * cq + 3], v.w);
  }
}

// ====================== BN finalize + fused epilogue =======================
__global__ void bn_finalize_kernel(const float* __restrict__ sums,
                                   float* __restrict__ mv, int N) {
  int d = threadIdx.x;
  if (d < D) {
    float inv_n = 1.0f / (float)N;
    float mean = sums[d] * inv_n;
    float var = sums[D + d] * inv_n - mean * mean;
    mv[d] = mean;
    mv[D + d] = rsqrtf(fmaxf(var, 0.0f) + BN_EPS);
  }
}

__global__ __launch_bounds__(256) void final4_kernel(
    const float* __restrict__ x, const float* __restrict__ mv,
    const float* __restrict__ gamma, const float* __restrict__ beta,
    float* __restrict__ out, int total4) {
  int i = blockIdx.x * 256 + threadIdx.x;
  if (i >= total4) return;
  int q = i & 31;
  float4 m4 = ((const float4*)mv)[q];
  float4 s4 = ((const float4*)mv)[32 + q];
  float4 g4 = ((const float4*)gamma)[q];
  float4 b4 = ((const float4*)beta)[q];
  float4 v  = ((const float4*)out)[i];
  float4 xv = ((const float4*)x)[i];
  float4 r;
  r.x = fmaxf((v.x - m4.x) * s4.x * g4.x + b4.x, 0.f) + xv.x;
  r.y = fmaxf((v.y - m4.y) * s4.y * g4.y + b4.y, 0.f) + xv.y;
  r.z = fmaxf((v.z - m4.z) * s4.z * g4.z + b4.z, 0.f) + xv.z;
  r.w = fmaxf((v.w - m4.w) * s4.w * g4.w + b4.w, 0.f) + xv.w;
  ((float4*)out)[i] = r;
}

// ===========================================================================
extern "C" void kernel_launch(void* const* d_in, const int* in_sizes, int n_in,
                              void* d_out, int out_size, void* d_ws, size_t ws_size,
                              hipStream_t stream) {
  const float* x     = (const float*)d_in[0];
  const int*   ei    = (const int*)d_in[1];   // int32 (harness converts ints)
  const float* W     = (const float*)d_in[2];
  // d_in[3] = b : cancels in BatchNorm (constant per-feature shift), skipped.
  const float* gamma = (const float*)d_in[4];
  const float* beta  = (const float*)d_in[5];

  const int N = in_sizes[0] / D;   // 100000
  const int E = in_sizes[1] / 2;   // 600000
  const int NB = (N + 255) / 256;

  float* out = (float*)d_out;      // doubles as agg buffer
  char* ws = (char*)d_ws;

  size_t need = ((size_t)3 * N + 512 + (size_t)E + 4 * D) * sizeof(float);

  if (ws_size >= need && NB <= 512) {
    // ---- CSR path (no f32 atomics in the hot loop) ----
    int*   cnt      = (int*)ws;              // N   (reused as cursor)
    int*   offsets  = cnt + N;               // N
    float* dis      = (float*)(offsets + N); // N
    int*   partials = (int*)(dis + N);       // 512
    int*   csr_row  = partials + 512;        // E
    float* sums     = (float*)(csr_row + E); // 2D
    float* mv       = sums + 2 * D;          // 2D

    hipMemsetAsync(cnt, 0, (size_t)N * sizeof(int), stream);
    hipMemsetAsync(sums, 0, 2 * D * sizeof(float), stream);

    degree_i_kernel<<<(E + 255) / 256, 256, 0, stream>>>(ei + E, cnt, E);
    scanA_kernel<<<NB, 256, 0, stream>>>(cnt, dis, partials, N);
    scanB_kernel<<<1, 512, 0, stream>>>(partials, NB);
    scanC_kernel<<<NB, 256, 0, stream>>>(cnt, partials, offsets, N);
    hipMemsetAsync(cnt, 0, (size_t)N * sizeof(int), stream);  // -> cursor
    bucket_kernel<<<(E + 255) / 256, 256, 0, stream>>>(ei, offsets, cnt, csr_row, E);
    csr_agg_kernel<<<(N + 3) / 4, 256, 0, stream>>>(csr_row, offsets, dis, x, out, N, E);
    gemm_stats_kernel<<<GEMM_GRID, 256, 0, stream>>>(W, out, sums, N);
    bn_finalize_kernel<<<1, 128, 0, stream>>>(sums, mv, N);
    final4_kernel<<<(N * 32 + 255) / 256, 256, 0, stream>>>(x, mv, gamma, beta, out, N * 32);
  } else {
    // ---- fallback: proven atomic-scatter path ----
    float* deg  = (float*)ws;
    float* sums = deg + N;
    float* mv   = sums + 2 * D;
    hipMemsetAsync(deg, 0, (size_t)N * sizeof(float), stream);
    hipMemsetAsync(sums, 0, 2 * D * sizeof(float), stream);
    hipMemsetAsync(out, 0, (size_t)out_size * sizeof(float), stream);
    degree_f_kernel<<<(E + 255) / 256, 256, 0, stream>>>(ei + E, deg, E);
    dis_kernel<<<(N + 255) / 256, 256, 0, stream>>>(deg, N);
    scatter_kernel<<<(E + 1) / 2, 256, 0, stream>>>(ei, x, deg, out, E);
    gemm_stats_kernel<<<GEMM_GRID, 256, 0, stream>>>(W, out, sums, N);
    bn_finalize_kernel<<<1, 128, 0, stream>>>(sums, mv, N);
    final4_kernel<<<(N * 32 + 255) / 256, 256, 0, stream>>>(x, mv, gamma, beta, out, N * 32);
  }
}

// Round 6
// 239.862 us; speedup vs baseline: 2.5663x; 1.0201x over previous
//
#include <hip/hip_runtime.h>

#define D 128
#define BN_EPS 1e-5f
#define GEMM_GRID 512
#define GEMM_TILE 32

// ============================ CSR build ====================================
__global__ __launch_bounds__(256) void degree_i_kernel(
    const int* __restrict__ col, int* __restrict__ cnt, int E) {
  int e = blockIdx.x * 256 + threadIdx.x;
  if (e < E) atomicAdd(&cnt[col[e]], 1);
}

// per-block sums of cnt + dis = rsqrt(cnt)
__global__ __launch_bounds__(256) void scanA_kernel(
    const int* __restrict__ cnt, float* __restrict__ dis,
    int* __restrict__ partials, int N) {
  __shared__ int l[256];
  int t = threadIdx.x;
  int i = blockIdx.x * 256 + t;
  int v = (i < N) ? cnt[i] : 0;
  if (i < N) dis[i] = (v > 0) ? rsqrtf((float)v) : 0.0f;
  l[t] = v; __syncthreads();
  for (int s = 128; s > 0; s >>= 1) {
    if (t < s) l[t] += l[t + s];
    __syncthreads();
  }
  if (t == 0) partials[blockIdx.x] = l[0];
}

// single-block exclusive scan of partials (nb <= 512)
__global__ void scanB_kernel(int* __restrict__ partials, int nb) {
  __shared__ int l[512];
  int t = threadIdx.x;
  l[t] = (t < nb) ? partials[t] : 0;
  __syncthreads();
  for (int off = 1; off < 512; off <<= 1) {
    int v = (t >= off) ? l[t - off] : 0;
    __syncthreads();
    l[t] += v;
    __syncthreads();
  }
  if (t < nb) partials[t] = (t == 0) ? 0 : l[t - 1];
}

// per-element exclusive offsets
__global__ __launch_bounds__(256) void scanC_kernel(
    const int* __restrict__ cnt, const int* __restrict__ partials,
    int* __restrict__ offsets, int N) {
  __shared__ int l[256];
  int t = threadIdx.x;
  int i = blockIdx.x * 256 + t;
  int v = (i < N) ? cnt[i] : 0;
  l[t] = v; __syncthreads();
  for (int off = 1; off < 256; off <<= 1) {
    int u = (t >= off) ? l[t - off] : 0;
    __syncthreads();
    l[t] += u;
    __syncthreads();
  }
  if (i < N) offsets[i] = partials[blockIdx.x] + l[t] - v;
}

// scatter edge source-ids into destination-sorted order
__global__ __launch_bounds__(256) void bucket_kernel(
    const int* __restrict__ ei, const int* __restrict__ offsets,
    int* __restrict__ cursor, int* __restrict__ csr_row, int E) {
  int e = blockIdx.x * 256 + threadIdx.x;
  if (e < E) {
    int c = ei[E + e];
    int p = offsets[c] + atomicAdd(&cursor[c], 1);
    csr_row[p] = ei[e];
  }
}

// ==================== x -> bf16 (RNE) conversion pass ======================
// unit = 8 consecutive floats -> uint4 of 8 bf16
__global__ __launch_bounds__(256) void cvt_bf16_kernel(
    const float* __restrict__ x, uint4* __restrict__ xb, int total8) {
  int i = blockIdx.x * 256 + threadIdx.x;
  if (i >= total8) return;
  const float4* x4 = (const float4*)x;
  float4 a = x4[(size_t)i * 2];
  float4 b = x4[(size_t)i * 2 + 1];
  float f[8] = {a.x, a.y, a.z, a.w, b.x, b.y, b.z, b.w};
  unsigned int h[8];
#pragma unroll
  for (int j = 0; j < 8; ++j) {
    unsigned int bits = __float_as_uint(f[j]);
    h[j] = (bits + 0x7fffu + ((bits >> 16) & 1u)) >> 16;  // RNE
  }
  uint4 o;
  o.x = h[0] | (h[1] << 16);
  o.y = h[2] | (h[3] << 16);
  o.z = h[4] | (h[5] << 16);
  o.w = h[6] | (h[7] << 16);
  xb[i] = o;
}

// ================= aggregation: gather bf16 rows, write once ===============
// wave per node; quarter-wave (16 lanes x uint4 = 256B) per edge -> 4 edges
// in flight; f32 accumulate; shfl_xor(16,32) combine.
__global__ __launch_bounds__(256) void csr_agg_bf16_kernel(
    const int* __restrict__ csr_row, const int* __restrict__ offsets,
    const float* __restrict__ dis, const uint4* __restrict__ xb,
    float* __restrict__ out, int N, int E) {
  int wave = threadIdx.x >> 6;
  int lane = threadIdx.x & 63;
  int q    = lane >> 4;     // edge slot 0..3
  int l16  = lane & 15;     // 16B chunk within row (8 bf16)
  int c = blockIdx.x * 4 + wave;
  if (c >= N) return;
  int s = offsets[c];
  int e = (c + 1 < N) ? offsets[c + 1] : E;
  float acc[8] = {};
  for (int i = s + q; i < e; i += 4) {
    int r = csr_row[i];
    float w = dis[r];
    uint4 v = xb[(size_t)r * 16 + l16];
    acc[0] = fmaf(w, __uint_as_float(v.x << 16),          acc[0]);
    acc[1] = fmaf(w, __uint_as_float(v.x & 0xffff0000u),  acc[1]);
    acc[2] = fmaf(w, __uint_as_float(v.y << 16),          acc[2]);
    acc[3] = fmaf(w, __uint_as_float(v.y & 0xffff0000u),  acc[3]);
    acc[4] = fmaf(w, __uint_as_float(v.z << 16),          acc[4]);
    acc[5] = fmaf(w, __uint_as_float(v.z & 0xffff0000u),  acc[5]);
    acc[6] = fmaf(w, __uint_as_float(v.w << 16),          acc[6]);
    acc[7] = fmaf(w, __uint_as_float(v.w & 0xffff0000u),  acc[7]);
  }
#pragma unroll
  for (int j = 0; j < 8; ++j) {
    acc[j] += __shfl_xor(acc[j], 16, 64);
    acc[j] += __shfl_xor(acc[j], 32, 64);
  }
  if (q == 0) {
    float wc = dis[c];
    float4 o0 = make_float4(acc[0]*wc, acc[1]*wc, acc[2]*wc, acc[3]*wc);
    float4 o1 = make_float4(acc[4]*wc, acc[5]*wc, acc[6]*wc, acc[7]*wc);
    ((float4*)out)[(size_t)c * 32 + l16 * 2]     = o0;
    ((float4*)out)[(size_t)c * 32 + l16 * 2 + 1] = o1;
  }
}

// ============== f32 gather fallback (round-4 proven version) ===============
__global__ __launch_bounds__(256) void csr_agg_kernel(
    const int* __restrict__ csr_row, const int* __restrict__ offsets,
    const float* __restrict__ dis, const float* __restrict__ x,
    float* __restrict__ out, int N, int E) {
  int wave = threadIdx.x >> 6;
  int lane = threadIdx.x & 63;
  int half = lane >> 5;
  int d4   = lane & 31;
  int c = blockIdx.x * 4 + wave;
  if (c >= N) return;
  int s = offsets[c];
  int e = (c + 1 < N) ? offsets[c + 1] : E;
  const float4* x4 = (const float4*)x;
  float4 a0 = {0.f, 0.f, 0.f, 0.f};
  int i = s + half;
  for (; i < e; i += 2) {
    int r = csr_row[i];
    float w = dis[r];
    float4 v = x4[(size_t)r * 32 + d4];
    a0.x = fmaf(w, v.x, a0.x); a0.y = fmaf(w, v.y, a0.y);
    a0.z = fmaf(w, v.z, a0.z); a0.w = fmaf(w, v.w, a0.w);
  }
  a0.x += __shfl_xor(a0.x, 32, 64);
  a0.y += __shfl_xor(a0.y, 32, 64);
  a0.z += __shfl_xor(a0.z, 32, 64);
  a0.w += __shfl_xor(a0.w, 32, 64);
  if (half == 0) {
    float wc = dis[c];
    a0.x *= wc; a0.y *= wc; a0.z *= wc; a0.w *= wc;
    ((float4*)out)[(size_t)c * 32 + d4] = a0;
  }
}

// ====================== fallback aggregation (atomics) =====================
__global__ __launch_bounds__(256) void degree_f_kernel(
    const int* __restrict__ col, float* __restrict__ deg, int E) {
  int e = blockIdx.x * 256 + threadIdx.x;
  if (e < E) atomicAdd(&deg[col[e]], 1.0f);
}
__global__ __launch_bounds__(256) void dis_kernel(float* __restrict__ deg, int N) {
  int n = blockIdx.x * 256 + threadIdx.x;
  if (n < N) {
    float d = deg[n];
    deg[n] = (d > 0.0f) ? rsqrtf(fmaxf(d, 1.0f)) : 0.0f;
  }
}
__global__ __launch_bounds__(256) void scatter_kernel(
    const int* __restrict__ ei, const float* __restrict__ x,
    const float* __restrict__ dis, float* __restrict__ out, int E) {
  int e = blockIdx.x * 2 + (threadIdx.x >> 7);
  int d = threadIdx.x & 127;
  if (e >= E) return;
  int r = ei[e];
  int c = ei[E + e];
  float norm = dis[r] * dis[c];
  atomicAdd(&out[(size_t)c * D + d], x[(size_t)r * D + d] * norm);
}

// ===== in-place GEMM (W in LDS) + fused BN stats, reg-prefetch dbuf =======
// 256 threads: rp = t>>5 -> rows 4rp..4rp+3, cq = t&31 -> cols 4cq..4cq+3.
__global__ __launch_bounds__(256) void gemm_stats_kernel(
    const float* __restrict__ W, float* __restrict__ out,
    float* __restrict__ sums, int N) {
  __shared__ float Wl[D * D];                 // 64 KB
  __shared__ float4 xs4[GEMM_TILE][D / 4];    // 16 KB
  int t = threadIdx.x;
  {
    const float4* W4 = (const float4*)W;
    float4* Wl4w = (float4*)Wl;
#pragma unroll
    for (int i = 0; i < 16; ++i)
      Wl4w[i * 256 + t] = W4[i * 256 + t];
  }
  const float4* Wl4 = (const float4*)Wl;
  const float4* o4r = (const float4*)out;
  float4* o4w = (float4*)out;
  int rp = t >> 5;
  int cq = t & 31;
  int r0 = rp * 4;
  float sA0=0,sA1=0,sA2=0,sA3=0, sQ0=0,sQ1=0,sQ2=0,sQ3=0;
  size_t total4 = (size_t)N * 32;

  // prefetch first tile into registers
  float4 pf[4];
  int base = blockIdx.x * GEMM_TILE;
#pragma unroll
  for (int i = 0; i < 4; ++i) {
    size_t idx = (size_t)base * 32 + t + i * 256;
    pf[i] = (idx < total4) ? o4r[idx] : make_float4(0.f, 0.f, 0.f, 0.f);
  }

  for (; base < N; base += GEMM_GRID * GEMM_TILE) {
    __syncthreads();                 // xs4 free (previous compute done)
#pragma unroll
    for (int i = 0; i < 4; ++i)
      ((float4*)xs4)[t + i * 256] = pf[i];
    __syncthreads();                 // xs4 ready

    // issue next tile's loads now; compute hides their latency
    int nbase = base + GEMM_GRID * GEMM_TILE;
    if (nbase < N) {
#pragma unroll
      for (int i = 0; i < 4; ++i) {
        size_t idx = (size_t)nbase * 32 + t + i * 256;
        pf[i] = (idx < total4) ? o4r[idx] : make_float4(0.f, 0.f, 0.f, 0.f);
      }
    }

    int nrows = min(GEMM_TILE, N - base);
    float acc[4][4] = {};
    for (int k4 = 0; k4 < 32; ++k4) {
      float4 wv0 = Wl4[(k4 * 4 + 0) * 32 + cq];
      float4 wv1 = Wl4[(k4 * 4 + 1) * 32 + cq];
      float4 wv2 = Wl4[(k4 * 4 + 2) * 32 + cq];
      float4 wv3 = Wl4[(k4 * 4 + 3) * 32 + cq];
#pragma unroll
      for (int rr = 0; rr < 4; ++rr) {
        float4 xv = xs4[r0 + rr][k4];
        acc[rr][0] = fmaf(xv.x, wv0.x, acc[rr][0]);
        acc[rr][1] = fmaf(xv.x, wv0.y, acc[rr][1]);
        acc[rr][2] = fmaf(xv.x, wv0.z, acc[rr][2]);
        acc[rr][3] = fmaf(xv.x, wv0.w, acc[rr][3]);
        acc[rr][0] = fmaf(xv.y, wv1.x, acc[rr][0]);
        acc[rr][1] = fmaf(xv.y, wv1.y, acc[rr][1]);
        acc[rr][2] = fmaf(xv.y, wv1.z, acc[rr][2]);
        acc[rr][3] = fmaf(xv.y, wv1.w, acc[rr][3]);
        acc[rr][0] = fmaf(xv.z, wv2.x, acc[rr][0]);
        acc[rr][1] = fmaf(xv.z, wv2.y, acc[rr][1]);
        acc[rr][2] = fmaf(xv.z, wv2.z, acc[rr][2]);
        acc[rr][3] = fmaf(xv.z, wv2.w, acc[rr][3]);
        acc[rr][0] = fmaf(xv.w, wv3.x, acc[rr][0]);
        acc[rr][1] = fmaf(xv.w, wv3.y, acc[rr][1]);
        acc[rr][2] = fmaf(xv.w, wv3.z, acc[rr][2]);
        acc[rr][3] = fmaf(xv.w, wv3.w, acc[rr][3]);
      }
    }

#pragma unroll
    for (int rr = 0; rr < 4; ++rr) {
      if (r0 + rr < nrows) {
        o4w[(size_t)(base + r0 + rr) * 32 + cq] =
            make_float4(acc[rr][0], acc[rr][1], acc[rr][2], acc[rr][3]);
        sA0 += acc[rr][0]; sA1 += acc[rr][1]; sA2 += acc[rr][2]; sA3 += acc[rr][3];
        sQ0 += acc[rr][0]*acc[rr][0]; sQ1 += acc[rr][1]*acc[rr][1];
        sQ2 += acc[rr][2]*acc[rr][2]; sQ3 += acc[rr][3]*acc[rr][3];
      }
    }
  }

  // block-level stats reduction (reuse xs4), then 4 atomics per cq-thread
  float4* red = (float4*)xs4;
  __syncthreads();
  red[t] = make_float4(sA0, sA1, sA2, sA3);
  __syncthreads();
  if (rp == 0) {
    float4 v = red[cq];
#pragma unroll
    for (int r = 1; r < 8; ++r) {
      float4 u = red[r * 32 + cq];
      v.x += u.x; v.y += u.y; v.z += u.z; v.w += u.w;
    }
    atomicAdd(&sums[4 * cq + 0], v.x);
    atomicAdd(&sums[4 * cq + 1], v.y);
    atomicAdd(&sums[4 * cq + 2], v.z);
    atomicAdd(&sums[4 * cq + 3], v.w);
  }
  __syncthreads();
  red[t] = make_float4(sQ0, sQ1, sQ2, sQ3);
  __syncthreads();
  if (rp == 0) {
    float4 v = red[cq];
#pragma unroll
    for (int r = 1; r < 8; ++r) {
      float4 u = red[r * 32 + cq];
      v.x += u.x; v.y += u.y; v.z += u.z; v.w += u.w;
    }
    atomicAdd(&sums[D + 4 * cq + 0], v.x);
    atomicAdd(&sums[D + 4 * cq + 1], v.y);
    atomicAdd(&sums[D + 4 * cq + 2], v.z);
    atomicAdd(&sums[D + 4 * cq + 3], v.w);
  }
}

// ====================== BN finalize + fused epilogue =======================
__global__ void bn_finalize_kernel(const float* __restrict__ sums,
                                   float* __restrict__ mv, int N) {
  int d = threadIdx.x;
  if (d < D) {
    float inv_n = 1.0f / (float)N;
    float mean = sums[d] * inv_n;
    float var = sums[D + d] * inv_n - mean * mean;
    mv[d] = mean;
    mv[D + d] = rsqrtf(fmaxf(var, 0.0f) + BN_EPS);
  }
}

__global__ __launch_bounds__(256) void final4_kernel(
    const float* __restrict__ x, const float* __restrict__ mv,
    const float* __restrict__ gamma, const float* __restrict__ beta,
    float* __restrict__ out, int total4) {
  int i = blockIdx.x * 256 + threadIdx.x;
  if (i >= total4) return;
  int q = i & 31;
  float4 m4 = ((const float4*)mv)[q];
  float4 s4 = ((const float4*)mv)[32 + q];
  float4 g4 = ((const float4*)gamma)[q];
  float4 b4 = ((const float4*)beta)[q];
  float4 v  = ((const float4*)out)[i];
  float4 xv = ((const float4*)x)[i];
  float4 r;
  r.x = fmaxf((v.x - m4.x) * s4.x * g4.x + b4.x, 0.f) + xv.x;
  r.y = fmaxf((v.y - m4.y) * s4.y * g4.y + b4.y, 0.f) + xv.y;
  r.z = fmaxf((v.z - m4.z) * s4.z * g4.z + b4.z, 0.f) + xv.z;
  r.w = fmaxf((v.w - m4.w) * s4.w * g4.w + b4.w, 0.f) + xv.w;
  ((float4*)out)[i] = r;
}

// ===========================================================================
extern "C" void kernel_launch(void* const* d_in, const int* in_sizes, int n_in,
                              void* d_out, int out_size, void* d_ws, size_t ws_size,
                              hipStream_t stream) {
  const float* x     = (const float*)d_in[0];
  const int*   ei    = (const int*)d_in[1];   // int32 (harness converts ints)
  const float* W     = (const float*)d_in[2];
  // d_in[3] = b : cancels in BatchNorm (constant per-feature shift), skipped.
  const float* gamma = (const float*)d_in[4];
  const float* beta  = (const float*)d_in[5];

  const int N = in_sizes[0] / D;   // 100000
  const int E = in_sizes[1] / 2;   // 600000
  const int NB = (N + 255) / 256;

  float* out = (float*)d_out;      // doubles as agg buffer
  char* ws = (char*)d_ws;

  size_t need_csr  = ((size_t)3 * N + 512 + (size_t)E + 4 * D) * sizeof(float);
  size_t need_bf16 = need_csr + (size_t)N * D * sizeof(unsigned short);

  if (ws_size >= need_csr && NB <= 512) {
    // ---- CSR path ----
    int*   cnt      = (int*)ws;              // N   (reused as cursor)
    int*   offsets  = cnt + N;               // N
    float* dis      = (float*)(offsets + N); // N
    int*   partials = (int*)(dis + N);       // 512
    int*   csr_row  = partials + 512;        // E
    float* sums     = (float*)(csr_row + E); // 2D
    float* mv       = sums + 2 * D;          // 2D
    uint4* xb       = (uint4*)(mv + 2 * D);  // N*D bf16 (if it fits)

    hipMemsetAsync(cnt, 0, (size_t)N * sizeof(int), stream);
    hipMemsetAsync(sums, 0, 2 * D * sizeof(float), stream);

    degree_i_kernel<<<(E + 255) / 256, 256, 0, stream>>>(ei + E, cnt, E);
    scanA_kernel<<<NB, 256, 0, stream>>>(cnt, dis, partials, N);
    scanB_kernel<<<1, 512, 0, stream>>>(partials, NB);
    scanC_kernel<<<NB, 256, 0, stream>>>(cnt, partials, offsets, N);
    hipMemsetAsync(cnt, 0, (size_t)N * sizeof(int), stream);  // -> cursor
    bucket_kernel<<<(E + 255) / 256, 256, 0, stream>>>(ei, offsets, cnt, csr_row, E);

    if (ws_size >= need_bf16) {
      int total8 = N * D / 8;
      cvt_bf16_kernel<<<(total8 + 255) / 256, 256, 0, stream>>>(x, xb, total8);
      csr_agg_bf16_kernel<<<(N + 3) / 4, 256, 0, stream>>>(csr_row, offsets, dis, xb, out, N, E);
    } else {
      csr_agg_kernel<<<(N + 3) / 4, 256, 0, stream>>>(csr_row, offsets, dis, x, out, N, E);
    }
    gemm_stats_kernel<<<GEMM_GRID, 256, 0, stream>>>(W, out, sums, N);
    bn_finalize_kernel<<<1, 128, 0, stream>>>(sums, mv, N);
    final4_kernel<<<(N * 32 + 255) / 256, 256, 0, stream>>>(x, mv, gamma, beta, out, N * 32);
  } else {
    // ---- fallback: proven atomic-scatter path ----
    float* deg  = (float*)ws;
    float* sums = deg + N;
    float* mv   = sums + 2 * D;
    hipMemsetAsync(deg, 0, (size_t)N * sizeof(float), stream);
    hipMemsetAsync(sums, 0, 2 * D * sizeof(float), stream);
    hipMemsetAsync(out, 0, (size_t)out_size * sizeof(float), stream);
    degree_f_kernel<<<(E + 255) / 256, 256, 0, stream>>>(ei + E, deg, E);
    dis_kernel<<<(N + 255) / 256, 256, 0, stream>>>(deg, N);
    scatter_kernel<<<(E + 1) / 2, 256, 0, stream>>>(ei, x, deg, out, E);
    gemm_stats_kernel<<<GEMM_GRID, 256, 0, stream>>>(W, out, sums, N);
    bn_finalize_kernel<<<1, 128, 0, stream>>>(sums, mv, N);
    final4_kernel<<<(N * 32 + 255) / 256, 256, 0, stream>>>(x, mv, gamma, beta, out, N * 32);
  }
}